// Round 18
// baseline (1692.487 us; speedup 1.0000x reference)
//
#include <hip/hip_runtime.h>
#include <hip/hip_fp16.h>

#define NATOMS 24
#define HIDD   61
#define NITERS 6
#define CTOT   132        // c-slots: 128 real + 1 bias + 3 zero
#define QS     33         // c-slots per K-quarter

typedef unsigned short u16;
typedef unsigned int   u32;
typedef _Float16 f16x8 __attribute__((ext_vector_type(8)));
typedef float    f32x4 __attribute__((ext_vector_type(4)));

#define GLOAD_LDS16(g, l) __builtin_amdgcn_global_load_lds( \
    (const __attribute__((address_space(1))) void*)(g), \
    (__attribute__((address_space(3))) void*)(l), 16, 0, 0)

__device__ __forceinline__ float sigm(float x){ return 1.f/(1.f + __expf(-x)); }
__device__ __forceinline__ float tanhx(float x){ return 1.f - 2.f/(__expf(2.f*x)+1.f); }
__device__ __forceinline__ u16 f2h(float f){ return __half_as_ushort(__float2half(f)); }
__device__ __forceinline__ float hbits2f(u16 b){
  union { u16 u; __half h; } cv; cv.u = b; return __half2float(cv.h);
}

__device__ __forceinline__ f16x8 vmul8(f16x8 v, _Float16 s){
  f16x8 r;
  #pragma unroll
  for (int i=0;i<8;++i) r[i] = v[i]*s;
  return r;
}

// ---------------------------------------------------------------------------
__global__ void k_init_h(const int* __restrict__ x, const float* __restrict__ embed,
                         const float* __restrict__ ext, float* __restrict__ h, int N){
  int t = blockIdx.x*blockDim.x + threadIdx.x;
  if (t >= N*64) return;
  int n = t >> 6, k = t & 63;
  float v;
  if (k < HIDD) v = fmaxf(embed[x[n]*HIDD + k], 0.f);
  else          v = ext[n*3 + (k - HIDD)];
  h[t] = v;
}

// ---------------------------------------------------------------------------
// B_glob: fp16 frag-layout of We2R (+bias row c=128, zeros c=129..131),
// 8KB per c-slot: frag fi = c*8 + kh*4 + ct.
__global__ void k_prep_B(const float* __restrict__ We2, const float* __restrict__ be2,
                         u16* __restrict__ Bg){
  int tid = blockIdx.x*blockDim.x + threadIdx.x;
  if (tid >= CTOT*8*64) return;
  int l  = tid & 63;
  int fi = tid >> 6;
  int ct = fi & 3;
  int kh = (fi >> 2) & 1;
  int c  = fi >> 3;
  int n  = ct*16 + (l & 15);
  int hb = kh*32 + (l >> 4)*8;
  u16 ov[8];
  #pragma unroll
  for (int j=0;j<8;++j){
    int hh = hb + j;
    float v = 0.f;
    if (c < 128)       v = We2[(size_t)c*4096 + hh*64 + n];
    else if (c == 128) v = be2[hh*64 + n];
    ov[j] = f2h(v);
  }
  uint4 o;
  o.x = (u32)ov[0] | ((u32)ov[1]<<16);
  o.y = (u32)ov[2] | ((u32)ov[3]<<16);
  o.z = (u32)ov[4] | ((u32)ov[5]<<16);
  o.w = (u32)ov[6] | ((u32)ov[7]<<16);
  *(uint4*)&Bg[(size_t)fi*512 + l*8] = o;
}

// ---------------------------------------------------------------------------
// Weight frags for k_final: 80 frags x 512 u16.
__global__ void k_prep_W(const float* __restrict__ Wo1, const float* __restrict__ Wo2,
                         const float* __restrict__ Wc1, const float* __restrict__ Wc2,
                         u16* __restrict__ Wf){
  int tid = blockIdx.x*blockDim.x + threadIdx.x;
  if (tid >= 80*64) return;
  int l  = tid & 63;
  int fi = tid >> 6;
  int lr = l & 15, lq = l >> 4;
  u16 ov[8];
  #pragma unroll
  for (int j=0;j<8;++j){
    float v = 0.f;
    if (fi < 8){
      int ct = fi >> 1, kh = fi & 1;
      int n = ct*16 + lr, k = kh*32 + lq*8 + j;
      v = Wo1[k*64 + n];
    } else if (fi < 16){
      int f2 = fi - 8;
      int ct = f2 >> 1, kh = f2 & 1;
      int n = ct*16 + lr, k = kh*32 + lq*8 + j;
      v = Wo2[k*64 + n];
    } else if (fi < 64){
      int f2 = fi - 16;
      int cti = f2 / 3, kh = f2 % 3;
      int n = cti*16 + lr, k = kh*32 + lq*8 + j;
      if (k < 91) v = Wc1[k*256 + n];
    } else {
      int f2 = fi - 64;
      int kh = f2 >> 1, ct = f2 & 1;
      int n = ct*16 + lr, k = kh*32 + lq*8 + j;
      if (n < 18) v = Wc2[k*18 + n];
    }
    ov[j] = f2h(v);
  }
  uint4 o;
  o.x = (u32)ov[0] | ((u32)ov[1]<<16);
  o.y = (u32)ov[2] | ((u32)ov[3]<<16);
  o.z = (u32)ov[4] | ((u32)ov[5]<<16);
  o.w = (u32)ov[6] | ((u32)ov[7]<<16);
  *(uint4*)&Wf[(size_t)fi*512 + l*8] = o;
}

// ---------------------------------------------------------------------------
// Combine weight frags: 56 frags x 512 u16 (unchanged from r17).
__global__ void k_prep_C(const float* __restrict__ root, const float* __restrict__ Wih,
                         const float* __restrict__ Whh, u16* __restrict__ Cf){
  int tid = blockIdx.x*blockDim.x + threadIdx.x;
  if (tid >= 56*64) return;
  int l  = tid & 63;
  int fi = tid >> 6;
  int lr = l & 15, lq = l >> 4;
  u16 ov[8];
  #pragma unroll
  for (int j=0;j<8;++j){
    float v;
    int k = (fi < 8 ? (fi & 1) : ((fi - 8) & 1)) * 32 + lq*8 + j;
    if (fi < 8){
      int ct = fi >> 1;
      v = root[k*64 + ct*16 + lr];
    } else if (fi < 32){
      int cti = (fi - 8) >> 1;
      v = Wih[(cti*16 + lr)*64 + k];
    } else {
      int cti = (fi - 32) >> 1;
      v = Whh[(cti*16 + lr)*64 + k];
    }
    ov[j] = f2h(v);
  }
  uint4 o;
  o.x = (u32)ov[0] | ((u32)ov[1]<<16);
  o.y = (u32)ov[2] | ((u32)ov[3]<<16);
  o.z = (u32)ov[4] | ((u32)ov[5]<<16);
  o.w = (u32)ov[6] | ((u32)ov[7]<<16);
  *(uint4*)&Cf[(size_t)fi*512 + l*8] = o;
}

// ---------------------------------------------------------------------------
// A_glob TRANSPOSED: AgT[e][CTOT] fp16.
__global__ __launch_bounds__(256) void k_edge_mlp(
    const float* __restrict__ ea, const float* __restrict__ We1,
    const float* __restrict__ be1, u16* __restrict__ AgT, int E, int Epad)
{
  __shared__ float Al[128][66];
  int t = threadIdx.x;
  int e0 = blockIdx.x * 64;
  int el = t & 63, cg = t >> 6;
  int e = e0 + el;
  float4 av = make_float4(0,0,0,0);
  if (e < E) av = *(const float4*)&ea[(size_t)e*4];
  for (int cc = 0; cc < 32; ++cc){
    int c = cg*32 + cc;
    float v = be1[c] + av.x*We1[c] + av.y*We1[128+c] + av.z*We1[256+c] + av.w*We1[384+c];
    Al[c][el] = fmaxf(v, 0.f);
  }
  __syncthreads();
  for (int idx = t; idx < 64*33; idx += 256){
    int el2 = idx / 33, q = idx % 33;
    u16 ov[4];
    #pragma unroll
    for (int i=0;i<4;++i){
      int c = q*4 + i;
      float v;
      if (c < 128)       v = Al[c][el2];
      else if (c == 128) v = 1.f;
      else               v = 0.f;
      ov[i] = f2h(v);
    }
    ushort4 o; o.x=ov[0]; o.y=ov[1]; o.z=ov[2]; o.w=ov[3];
    *(ushort4*)&AgT[(size_t)(e0+el2)*CTOT + q*4] = o;
  }
}

// ---------------------------------------------------------------------------
// Fused msg + segment_sum via MFMA, v13: 1024 thr = 16 waves = eg(4, 32
// edges; the proven rt=2/VGPR-56 body) x quarter(4, 33 c-slots of 8 KB,
// double-buffered). LDS 64.6 KB -> 2 blocks/CU -> ~29 waves/CU from the
// 470-block grid (2x v10). 33 barriers/block (v10 density). Epilogue:
// 4-way LDS tree reduce across quarters; q0 issues one atomic per element.
__global__ __launch_bounds__(1024,8) void k_msg_mfma(
    const int* __restrict__ ei, const float* __restrict__ h,
    const u16* __restrict__ AgT, const u16* __restrict__ Bg,
    float* __restrict__ agg, int E, int Epad)
{
  __shared__ __align__(16) u16 Blds[4][2][4096];  // [quarter][buf][8KB]
  __shared__ int dstl[128];
  int t = threadIdx.x;
  int lane = t & 63;
  int w = t >> 6;            // 0..15
  int eg = w & 3;            // 32-edge group
  int q  = w >> 2;           // K quarter
  int e0 = blockIdx.x * 128;
  int slot0 = q * QS;

  if (t < 128) dstl[t] = (e0 + t < E) ? ei[E + e0 + t] : -1;

  // v-frags: lane holds v[e][hb..hb+8), e = eg*32 + rt*16 + (lane&15),
  // hb = kh*32 + (lane>>4)*8.
  f16x8 vf[2][2];
  #pragma unroll
  for (int rt=0; rt<2; ++rt){
    int e = e0 + eg*32 + rt*16 + (lane&15);
    int src = (e < E) ? ei[e] : 0;
    const float* hp = &h[(size_t)src*64 + (lane>>4)*8];
    #pragma unroll
    for (int kh=0; kh<2; ++kh){
      float4 a = *(const float4*)&hp[kh*32];
      float4 b = *(const float4*)&hp[kh*32+4];
      f16x8 v;
      v[0]=(_Float16)a.x; v[1]=(_Float16)a.y; v[2]=(_Float16)a.z; v[3]=(_Float16)a.w;
      v[4]=(_Float16)b.x; v[5]=(_Float16)b.y; v[6]=(_Float16)b.z; v[7]=(_Float16)b.w;
      vf[rt][kh] = v;
    }
  }

  f32x4 acc[2][4];
  #pragma unroll
  for (int i=0;i<2;++i)
    #pragma unroll
    for (int j=0;j<4;++j)
      acc[i][j] = (f32x4){0.f,0.f,0.f,0.f};

  const u16* Ae[2];
  #pragma unroll
  for (int rt=0; rt<2; ++rt)
    Ae[rt] = AgT + (size_t)(e0 + eg*32 + rt*16 + (lane&15))*CTOT + slot0;

  _Float16 arP[2], arN[2];
  #pragma unroll
  for (int rt=0;rt<2;++rt) arP[rt] = *(const _Float16*)&Ae[rt][0];

  // prologue: stage slot0 -> buf 0 (8 KB: 2 rounds x 4 egs x 64 lanes x 16B)
  {
    const char* g = (const char*)(Bg + (size_t)slot0*4096);
    #pragma unroll
    for (int r=0;r<2;++r)
      GLOAD_LDS16(g + r*4096 + eg*1024 + lane*16,
                  (char*)&Blds[q][0][0] + r*4096 + eg*1024);
  }
  __syncthreads();

  int cur = 0;
  for (int ci = 0; ci < QS; ++ci){
    if (ci + 1 < QS){
      const char* g = (const char*)(Bg + (size_t)(slot0 + ci + 1)*4096);
      #pragma unroll
      for (int r=0;r<2;++r)
        GLOAD_LDS16(g + r*4096 + eg*1024 + lane*16,
                    (char*)&Blds[q][cur^1][0] + r*4096 + eg*1024);
      #pragma unroll
      for (int rt=0;rt<2;++rt) arN[rt] = *(const _Float16*)&Ae[rt][ci+1];
    }
    const u16* Bb = &Blds[q][cur][0];
    #pragma unroll
    for (int kh=0; kh<2; ++kh){
      f16x8 g0 = vmul8(vf[0][kh], arP[0]);
      f16x8 g1 = vmul8(vf[1][kh], arP[1]);
      #pragma unroll
      for (int ct=0; ct<4; ++ct){
        f16x8 bf = *(const f16x8*)&Bb[(kh*4+ct)*512 + lane*8];
        acc[0][ct] = __builtin_amdgcn_mfma_f32_16x16x32_f16(g0, bf, acc[0][ct], 0,0,0);
        acc[1][ct] = __builtin_amdgcn_mfma_f32_16x16x32_f16(g1, bf, acc[1][ct], 0,0,0);
      }
    }
    __syncthreads();
    #pragma unroll
    for (int rt=0;rt<2;++rt) arP[rt] = arN[rt];
    cur ^= 1;
  }

  // ---- cross-quarter tree reduce via LDS (B buffers dead; 8 regions x 8 KB).
  // region layout: accl[reg*2048 + (rt*4+ct)*256 + lane*4] f32x4 — stride-1
  // b128, conflict-free.
  float* accl = (float*)&Blds[0][0][0];
  if (q >= 2){
    int reg = (q-2)*4 + eg;
    #pragma unroll
    for (int rt=0; rt<2; ++rt)
      #pragma unroll
      for (int ct=0; ct<4; ++ct)
        *(f32x4*)&accl[(size_t)reg*2048 + (rt*4+ct)*256 + lane*4] = acc[rt][ct];
  }
  __syncthreads();
  if (q < 2){
    int reg = q*4 + eg;       // q0 absorbs q2's dump, q1 absorbs q3's
    #pragma unroll
    for (int rt=0; rt<2; ++rt)
      #pragma unroll
      for (int ct=0; ct<4; ++ct)
        acc[rt][ct] += *(const f32x4*)&accl[(size_t)reg*2048 + (rt*4+ct)*256 + lane*4];
  }
  __syncthreads();
  if (q == 1){
    #pragma unroll
    for (int rt=0; rt<2; ++rt)
      #pragma unroll
      for (int ct=0; ct<4; ++ct)
        *(f32x4*)&accl[(size_t)eg*2048 + (rt*4+ct)*256 + lane*4] = acc[rt][ct];
  }
  __syncthreads();
  if (q == 0){
    #pragma unroll
    for (int rt=0; rt<2; ++rt)
      #pragma unroll
      for (int ct=0; ct<4; ++ct)
        acc[rt][ct] += *(const f32x4*)&accl[(size_t)eg*2048 + (rt*4+ct)*256 + lane*4];
    // epilogue: one atomic per edge-k element. D layout: col=lane&15,
    // row=(lane>>4)*4+reg.
    #pragma unroll
    for (int rt=0; rt<2; ++rt){
      #pragma unroll
      for (int r=0; r<4; ++r){
        int el = eg*32 + rt*16 + (lane>>4)*4 + r;
        int dv = dstl[el];
        if (dv >= 0){
          #pragma unroll
          for (int ct=0; ct<4; ++ct)
            unsafeAtomicAdd(&agg[(size_t)dv*64 + ct*16 + (lane&15)], acc[rt][ct][r]);
        }
      }
    }
  }
}

// ---------------------------------------------------------------------------
// combine v3 (MFMA, unchanged from r17).
__global__ __launch_bounds__(256) void k_combine(
    const float* __restrict__ hcur, float* __restrict__ agg,
    const u16* __restrict__ Cf, const float* __restrict__ convb,
    const float* __restrict__ bih, const float* __restrict__ bhh,
    float* __restrict__ hnext, int N)
{
  __shared__ __align__(16) u16  hn[32][72];    // h fp16 (node-major)
  __shared__ __align__(16) u16  mn[32][72];    // m fp16
  __shared__ float hsf[32][68];                // h fp32 (for GRU blend)
  int t = threadIdx.x;
  int lane = t & 63;
  int w = t >> 6;
  int lr = lane & 15, lq = lane >> 4;
  int n0 = blockIdx.x * 32;

  {
    int node = t >> 3, k8 = (t & 7) * 8;
    int n = n0 + node;
    f16x8 v;
    float4 a = make_float4(0,0,0,0), b = make_float4(0,0,0,0);
    if (n < N){
      a = *(const float4*)&hcur[(size_t)n*64 + k8];
      b = *(const float4*)&hcur[(size_t)n*64 + k8 + 4];
    }
    v[0]=(_Float16)a.x; v[1]=(_Float16)a.y; v[2]=(_Float16)a.z; v[3]=(_Float16)a.w;
    v[4]=(_Float16)b.x; v[5]=(_Float16)b.y; v[6]=(_Float16)b.z; v[7]=(_Float16)b.w;
    *(f16x8*)&hn[node][k8] = v;
    *(float4*)&hsf[node][k8] = a;
    *(float4*)&hsf[node][k8+4] = b;
  }
  __syncthreads();

  // m phase: wave w -> cols w*16..+15
  {
    f32x4 acc[2];
    acc[0] = (f32x4){0.f,0.f,0.f,0.f}; acc[1] = (f32x4){0.f,0.f,0.f,0.f};
    #pragma unroll
    for (int kh=0; kh<2; ++kh){
      f16x8 bf = *(const f16x8*)&Cf[(size_t)(w*2 + kh)*512 + lane*8];
      #pragma unroll
      for (int rt=0; rt<2; ++rt){
        f16x8 af = *(const f16x8*)&hn[rt*16 + lr][kh*32 + lq*8];
        acc[rt] = __builtin_amdgcn_mfma_f32_16x16x32_f16(af, bf, acc[rt], 0,0,0);
      }
    }
    float cb = convb[w*16 + lr];
    #pragma unroll
    for (int rt=0; rt<2; ++rt){
      #pragma unroll
      for (int r=0; r<4; ++r){
        int node = rt*16 + lq*4 + r;
        int n = n0 + node;
        int col = w*16 + lr;
        float ag = 0.f;
        if (n < N){
          ag = agg[(size_t)n*64 + col];
          agg[(size_t)n*64 + col] = 0.f;
        }
        mn[node][col] = f2h(fmaxf(acc[rt][r] + ag + cb, 0.f));
      }
    }
  }
  __syncthreads();

  f32x4 gi[3][2], gh[3][2];
  #pragma unroll
  for (int s=0;s<3;++s)
    #pragma unroll
    for (int rt=0;rt<2;++rt){
      gi[s][rt] = (f32x4){0.f,0.f,0.f,0.f};
      gh[s][rt] = (f32x4){0.f,0.f,0.f,0.f};
    }
  #pragma unroll
  for (int s=0; s<3; ++s){
    int cti = s*4 + w;
    #pragma unroll
    for (int kh=0; kh<2; ++kh){
      f16x8 bfI = *(const f16x8*)&Cf[(size_t)(8  + cti*2 + kh)*512 + lane*8];
      f16x8 bfH = *(const f16x8*)&Cf[(size_t)(32 + cti*2 + kh)*512 + lane*8];
      #pragma unroll
      for (int rt=0; rt<2; ++rt){
        f16x8 am = *(const f16x8*)&mn[rt*16 + lr][kh*32 + lq*8];
        f16x8 ah = *(const f16x8*)&hn[rt*16 + lr][kh*32 + lq*8];
        gi[s][rt] = __builtin_amdgcn_mfma_f32_16x16x32_f16(am, bfI, gi[s][rt], 0,0,0);
        gh[s][rt] = __builtin_amdgcn_mfma_f32_16x16x32_f16(ah, bfH, gh[s][rt], 0,0,0);
      }
    }
  }

  {
    int j = w*16 + lr;
    float bI0 = bih[j], bI1 = bih[64 + j], bI2 = bih[128 + j];
    float bH0 = bhh[j], bH1 = bhh[64 + j], bH2 = bhh[128 + j];
    #pragma unroll
    for (int rt=0; rt<2; ++rt){
      #pragma unroll
      for (int r=0; r<4; ++r){
        int node = rt*16 + lq*4 + r;
        int n = n0 + node;
        if (n < N){
          float rr = sigm(gi[0][rt][r] + bI0 + gh[0][rt][r] + bH0);
          float zz = sigm(gi[1][rt][r] + bI1 + gh[1][rt][r] + bH1);
          float hold = hsf[node][j];
          float nn = tanhx(gi[2][rt][r] + bI2 + rr*(gh[2][rt][r] + bH2));
          hnext[(size_t)n*64 + j] = (1.f - zz)*nn + zz*hold;
        }
      }
    }
  }
}

// ---------------------------------------------------------------------------
// final v3 (MFMA, unchanged from r14).
__global__ __launch_bounds__(256) void k_final(
    const float* __restrict__ h, const int* __restrict__ x, const float* __restrict__ ext,
    const u16* __restrict__ Wf,
    const float* __restrict__ bo1, const float* __restrict__ bo2,
    const float* __restrict__ bc1, const float* __restrict__ bc2,
    float* __restrict__ fg_out, float* __restrict__ pred_out, int N)
{
  __shared__ __align__(16) u16 fgn[32][104];  // h -> out2 -> fg (cols 0..95)
  __shared__ __align__(16) u16 t1n[32][264];  // o1 (0..63) -> t1 (0..255)
  int t = threadIdx.x;
  int lane = t & 63;
  int w = t >> 6;
  int lr = lane & 15, lq = lane >> 4;
  int n0 = blockIdx.x * 32;

  {
    int node = t >> 3, k8 = (t & 7) * 8;
    int n = n0 + node;
    f16x8 v;
    if (n < N){
      float4 a = *(const float4*)&h[(size_t)n*64 + k8];
      float4 b = *(const float4*)&h[(size_t)n*64 + k8 + 4];
      v[0]=(_Float16)a.x; v[1]=(_Float16)a.y; v[2]=(_Float16)a.z; v[3]=(_Float16)a.w;
      v[4]=(_Float16)b.x; v[5]=(_Float16)b.y; v[6]=(_Float16)b.z; v[7]=(_Float16)b.w;
    } else {
      #pragma unroll
      for (int i=0;i<8;++i) v[i] = (_Float16)0.f;
    }
    *(f16x8*)&fgn[node][k8] = v;
    if (t < 160){
      int node2 = t / 5, qd = t % 5;
      *(uint4*)&fgn[node2][64 + qd*8] = make_uint4(0,0,0,0);
    }
  }
  __syncthreads();

  // P1: o1 = relu(h@Wo1 + bo1)
  {
    f32x4 acc[2];
    acc[0] = (f32x4){0.f,0.f,0.f,0.f}; acc[1] = (f32x4){0.f,0.f,0.f,0.f};
    #pragma unroll
    for (int kh=0; kh<2; ++kh){
      f16x8 bf = *(const f16x8*)&Wf[(size_t)(w*2 + kh)*512 + lane*8];
      #pragma unroll
      for (int rt=0; rt<2; ++rt){
        f16x8 af = *(const f16x8*)&fgn[rt*16 + lr][kh*32 + lq*8];
        acc[rt] = __builtin_amdgcn_mfma_f32_16x16x32_f16(af, bf, acc[rt], 0,0,0);
      }
    }
    float bv = bo1[w*16 + lr];
    #pragma unroll
    for (int rt=0; rt<2; ++rt)
      #pragma unroll
      for (int r=0; r<4; ++r)
        t1n[rt*16 + lq*4 + r][w*16 + lr] = f2h(fmaxf(acc[rt][r] + bv, 0.f));
  }
  __syncthreads();

  // P2: out2 = o1@Wo2 + bo2 -> fgn
  {
    f32x4 acc[2];
    acc[0] = (f32x4){0.f,0.f,0.f,0.f}; acc[1] = (f32x4){0.f,0.f,0.f,0.f};
    #pragma unroll
    for (int kh=0; kh<2; ++kh){
      f16x8 bf = *(const f16x8*)&Wf[(size_t)(8 + w*2 + kh)*512 + lane*8];
      #pragma unroll
      for (int rt=0; rt<2; ++rt){
        f16x8 af = *(const f16x8*)&t1n[rt*16 + lr][kh*32 + lq*8];
        acc[rt] = __builtin_amdgcn_mfma_f32_16x16x32_f16(af, bf, acc[rt], 0,0,0);
      }
    }
    float bv = bo2[w*16 + lr];
    #pragma unroll
    for (int rt=0; rt<2; ++rt)
      #pragma unroll
      for (int r=0; r<4; ++r)
        fgn[rt*16 + lq*4 + r][w*16 + lr] = f2h(acc[rt][r] + bv);
  }
  __syncthreads();

  if (t < 32){
    int ni = t, n = n0 + ni;
    if (n < N){
      int idxn = x[n];
      float e0=ext[n*3], e1=ext[n*3+1], e2=ext[n*3+2];
      float ss = 1.f + e0*e0 + e1*e1 + e2*e2;
      for (int j=0;j<64;++j){ float v = hbits2f(fgn[ni][j]); ss += v*v; }
      float rn = 1.f / fmaxf(sqrtf(ss), 1e-12f);
      for (int j=0;j<64;++j) fgn[ni][j] = f2h(hbits2f(fgn[ni][j])*rn);
      #pragma unroll
      for (int c=0;c<24;++c) fgn[ni][64+c] = (c==idxn) ? f2h(rn) : (u16)0;
      fgn[ni][88] = f2h(e0*rn); fgn[ni][89] = f2h(e1*rn); fgn[ni][90] = f2h(e2*rn);
    }
  }
  __syncthreads();

  for (int idx=t; idx<32*91; idx+=256){
    int ni = idx / 91, c = idx % 91;
    int n = n0 + ni;
    if (n < N) fg_out[(size_t)n*91 + c] = hbits2f(fgn[ni][c]);
  }

  // P5: t1 = relu(fg@Wc1 + bc1), K=96
  {
    f32x4 acc[2][4];
    #pragma unroll
    for (int i=0;i<2;++i)
      #pragma unroll
      for (int j=0;j<4;++j) acc[i][j] = (f32x4){0.f,0.f,0.f,0.f};
    #pragma unroll
    for (int kh=0; kh<3; ++kh){
      f16x8 af[2];
      #pragma unroll
      for (int rt=0; rt<2; ++rt)
        af[rt] = *(const f16x8*)&fgn[rt*16 + lr][kh*32 + lq*8];
      #pragma unroll
      for (int c4=0; c4<4; ++c4){
        int cti = w*4 + c4;
        f16x8 bf = *(const f16x8*)&Wf[(size_t)(16 + cti*3 + kh)*512 + lane*8];
        #pragma unroll
        for (int rt=0; rt<2; ++rt)
          acc[rt][c4] = __builtin_amdgcn_mfma_f32_16x16x32_f16(af[rt], bf, acc[rt][c4], 0,0,0);
      }
    }
    #pragma unroll
    for (int c4=0; c4<4; ++c4){
      float bv = bc1[w*64 + c4*16 + lr];
      #pragma unroll
      for (int rt=0; rt<2; ++rt)
        #pragma unroll
        for (int r=0; r<4; ++r)
          t1n[rt*16 + lq*4 + r][w*64 + c4*16 + lr] = f2h(fmaxf(acc[rt][c4][r] + bv, 0.f));
    }
  }
  __syncthreads();

  // P6: pred = t1@Wc2 + bc2
  {
    int rt = w >> 1, ct = w & 1;
    f32x4 acc = (f32x4){0.f,0.f,0.f,0.f};
    #pragma unroll
    for (int kh=0; kh<8; ++kh){
      f16x8 af = *(const f16x8*)&t1n[rt*16 + lr][kh*32 + lq*8];
      f16x8 bf = *(const f16x8*)&Wf[(size_t)(64 + kh*2 + ct)*512 + lane*8];
      acc = __builtin_amdgcn_mfma_f32_16x16x32_f16(af, bf, acc, 0,0,0);
    }
    int c = ct*16 + lr;
    if (c < 18){
      float bv = bc2[c];
      #pragma unroll
      for (int r=0; r<4; ++r){
        int n = n0 + rt*16 + lq*4 + r;
        if (n < N) pred_out[(size_t)n*18 + c] = acc[r] + bv;
      }
    }
  }
}

// ---------------------------------------------------------------------------
extern "C" void kernel_launch(void* const* d_in, const int* in_sizes, int n_in,
                              void* d_out, int out_size, void* d_ws, size_t ws_size,
                              hipStream_t stream)
{
  const int*   x    = (const int*)d_in[0];
  const int*   ei   = (const int*)d_in[1];
  const float* ea   = (const float*)d_in[2];
  const float* ext  = (const float*)d_in[3];
  const float* embed= (const float*)d_in[4];
  const float* We1  = (const float*)d_in[5];
  const float* be1  = (const float*)d_in[6];
  const float* We2  = (const float*)d_in[7];
  const float* be2  = (const float*)d_in[8];
  const float* root = (const float*)d_in[9];
  const float* convb= (const float*)d_in[10];
  const float* Wih  = (const float*)d_in[11];
  const float* Whh  = (const float*)d_in[12];
  const float* bih  = (const float*)d_in[13];
  const float* bhh  = (const float*)d_in[14];
  const float* Wo1  = (const float*)d_in[15];
  const float* bo1  = (const float*)d_in[16];
  const float* Wo2  = (const float*)d_in[17];
  const float* bo2  = (const float*)d_in[18];
  const float* Wc1  = (const float*)d_in[19];
  const float* bc1  = (const float*)d_in[20];
  const float* Wc2  = (const float*)d_in[21];
  const float* bc2  = (const float*)d_in[22];
  int N = in_sizes[0];
  int E = in_sizes[1] / 2;
  float* out = (float*)d_out;
  float* fg_out = out;
  float* pred_out = out + (size_t)N*91;

  int nblk256 = (E + 255) / 256;
  int Epad = nblk256 * 256;
  int nblk128 = (E + 127) / 128;

  char* w = (char*)d_ws;
  size_t remain = ws_size;
  auto alloc = [&](size_t bytes)->char*{
    size_t rb = (bytes + 255) & ~(size_t)255;
    if (rb > remain) return (char*)0;
    char* p = w; w += rb; remain -= rb; return p;
  };
  float* h_a  = (float*)alloc((size_t)N*64*4);
  float* h_b  = (float*)alloc((size_t)N*64*4);
  float* agg  = (float*)alloc((size_t)N*64*4);
  u16*   AgT  = (u16*)alloc((size_t)Epad*CTOT*2);
  u16*   Bg   = (u16*)alloc((size_t)CTOT*8192);
  u16*   Wf   = (u16*)alloc((size_t)80*512*2);
  u16*   Cf   = (u16*)alloc((size_t)56*512*2);
  if (!h_a || !h_b || !agg || !AgT || !Bg || !Wf || !Cf) return;

  k_init_h<<<dim3((N*64 + 255)/256), dim3(256), 0, stream>>>(x, embed, ext, h_a, N);
  k_prep_B<<<dim3((CTOT*8*64 + 255)/256), dim3(256), 0, stream>>>(We2, be2, Bg);
  k_prep_W<<<dim3((80*64 + 255)/256), dim3(256), 0, stream>>>(Wo1, Wo2, Wc1, Wc2, Wf);
  k_prep_C<<<dim3((56*64 + 255)/256), dim3(256), 0, stream>>>(root, Wih, Whh, Cf);
  k_edge_mlp<<<dim3(Epad/64), dim3(256), 0, stream>>>(ea, We1, be1, AgT, E, Epad);
  hipMemsetAsync(agg, 0, (size_t)N*64*4, stream);

  float* hc = h_a; float* hn = h_b;
  for (int it = 0; it < NITERS; ++it){
    k_msg_mfma<<<dim3(nblk128), dim3(1024), 0, stream>>>(ei, hc, AgT, Bg, agg, E, Epad);
    k_combine<<<dim3((N + 31)/32), dim3(256), 0, stream>>>(
        hc, agg, Cf, convb, bih, bhh, hn, N);
    float* tmp = hc; hc = hn; hn = tmp;
  }

  k_final<<<dim3((N + 31)/32), dim3(256), 0, stream>>>(
      hc, x, ext, Wf, bo1, bo2, bc1, bc2, fg_out, pred_out, N);
}

// Round 19
// 502.372 us; speedup vs baseline: 3.3690x; 3.3690x over previous
//
#include <hip/hip_runtime.h>
#include <hip/hip_fp16.h>

#define NATOMS 24
#define HIDD   61
#define NITERS 6
#define CTOT   132        // c-slots: 128 real + 1 bias + 3 zero
#define HC     66         // c-slots per K-half

typedef unsigned short u16;
typedef unsigned int   u32;
typedef _Float16 f16x8 __attribute__((ext_vector_type(8)));
typedef float    f32x4 __attribute__((ext_vector_type(4)));

#define GLOAD_LDS16(g, l) __builtin_amdgcn_global_load_lds( \
    (const __attribute__((address_space(1))) void*)(g), \
    (__attribute__((address_space(3))) void*)(l), 16, 0, 0)

__device__ __forceinline__ float sigm(float x){ return 1.f/(1.f + __expf(-x)); }
__device__ __forceinline__ float tanhx(float x){ return 1.f - 2.f/(__expf(2.f*x)+1.f); }
__device__ __forceinline__ u16 f2h(float f){ return __half_as_ushort(__float2half(f)); }
__device__ __forceinline__ float hbits2f(u16 b){
  union { u16 u; __half h; } cv; cv.u = b; return __half2float(cv.h);
}

__device__ __forceinline__ f16x8 vmul8(f16x8 v, _Float16 s){
  f16x8 r;
  #pragma unroll
  for (int i=0;i<8;++i) r[i] = v[i]*s;
  return r;
}

// ---------------------------------------------------------------------------
__global__ void k_init_h(const int* __restrict__ x, const float* __restrict__ embed,
                         const float* __restrict__ ext, float* __restrict__ h, int N){
  int t = blockIdx.x*blockDim.x + threadIdx.x;
  if (t >= N*64) return;
  int n = t >> 6, k = t & 63;
  float v;
  if (k < HIDD) v = fmaxf(embed[x[n]*HIDD + k], 0.f);
  else          v = ext[n*3 + (k - HIDD)];
  h[t] = v;
}

// ---------------------------------------------------------------------------
// B_glob: fp16 frag-layout of We2R (+bias row c=128, zeros c=129..131),
// 8KB per c-slot: frag fi = c*8 + kh*4 + ct.
__global__ void k_prep_B(const float* __restrict__ We2, const float* __restrict__ be2,
                         u16* __restrict__ Bg){
  int tid = blockIdx.x*blockDim.x + threadIdx.x;
  if (tid >= CTOT*8*64) return;
  int l  = tid & 63;
  int fi = tid >> 6;
  int ct = fi & 3;
  int kh = (fi >> 2) & 1;
  int c  = fi >> 3;
  int n  = ct*16 + (l & 15);
  int hb = kh*32 + (l >> 4)*8;
  u16 ov[8];
  #pragma unroll
  for (int j=0;j<8;++j){
    int hh = hb + j;
    float v = 0.f;
    if (c < 128)       v = We2[(size_t)c*4096 + hh*64 + n];
    else if (c == 128) v = be2[hh*64 + n];
    ov[j] = f2h(v);
  }
  uint4 o;
  o.x = (u32)ov[0] | ((u32)ov[1]<<16);
  o.y = (u32)ov[2] | ((u32)ov[3]<<16);
  o.z = (u32)ov[4] | ((u32)ov[5]<<16);
  o.w = (u32)ov[6] | ((u32)ov[7]<<16);
  *(uint4*)&Bg[(size_t)fi*512 + l*8] = o;
}

// ---------------------------------------------------------------------------
// Weight frags for k_final: 80 frags x 512 u16.
__global__ void k_prep_W(const float* __restrict__ Wo1, const float* __restrict__ Wo2,
                         const float* __restrict__ Wc1, const float* __restrict__ Wc2,
                         u16* __restrict__ Wf){
  int tid = blockIdx.x*blockDim.x + threadIdx.x;
  if (tid >= 80*64) return;
  int l  = tid & 63;
  int fi = tid >> 6;
  int lr = l & 15, lq = l >> 4;
  u16 ov[8];
  #pragma unroll
  for (int j=0;j<8;++j){
    float v = 0.f;
    if (fi < 8){
      int ct = fi >> 1, kh = fi & 1;
      int n = ct*16 + lr, k = kh*32 + lq*8 + j;
      v = Wo1[k*64 + n];
    } else if (fi < 16){
      int f2 = fi - 8;
      int ct = f2 >> 1, kh = f2 & 1;
      int n = ct*16 + lr, k = kh*32 + lq*8 + j;
      v = Wo2[k*64 + n];
    } else if (fi < 64){
      int f2 = fi - 16;
      int cti = f2 / 3, kh = f2 % 3;
      int n = cti*16 + lr, k = kh*32 + lq*8 + j;
      if (k < 91) v = Wc1[k*256 + n];
    } else {
      int f2 = fi - 64;
      int kh = f2 >> 1, ct = f2 & 1;
      int n = ct*16 + lr, k = kh*32 + lq*8 + j;
      if (n < 18) v = Wc2[k*18 + n];
    }
    ov[j] = f2h(v);
  }
  uint4 o;
  o.x = (u32)ov[0] | ((u32)ov[1]<<16);
  o.y = (u32)ov[2] | ((u32)ov[3]<<16);
  o.z = (u32)ov[4] | ((u32)ov[5]<<16);
  o.w = (u32)ov[6] | ((u32)ov[7]<<16);
  *(uint4*)&Wf[(size_t)fi*512 + l*8] = o;
}

// ---------------------------------------------------------------------------
// Combine weight frags: 56 frags x 512 u16.
__global__ void k_prep_C(const float* __restrict__ root, const float* __restrict__ Wih,
                         const float* __restrict__ Whh, u16* __restrict__ Cf){
  int tid = blockIdx.x*blockDim.x + threadIdx.x;
  if (tid >= 56*64) return;
  int l  = tid & 63;
  int fi = tid >> 6;
  int lr = l & 15, lq = l >> 4;
  u16 ov[8];
  #pragma unroll
  for (int j=0;j<8;++j){
    float v;
    int k = (fi < 8 ? (fi & 1) : ((fi - 8) & 1)) * 32 + lq*8 + j;
    if (fi < 8){
      int ct = fi >> 1;
      v = root[k*64 + ct*16 + lr];
    } else if (fi < 32){
      int cti = (fi - 8) >> 1;
      v = Wih[(cti*16 + lr)*64 + k];
    } else {
      int cti = (fi - 32) >> 1;
      v = Whh[(cti*16 + lr)*64 + k];
    }
    ov[j] = f2h(v);
  }
  uint4 o;
  o.x = (u32)ov[0] | ((u32)ov[1]<<16);
  o.y = (u32)ov[2] | ((u32)ov[3]<<16);
  o.z = (u32)ov[4] | ((u32)ov[5]<<16);
  o.w = (u32)ov[6] | ((u32)ov[7]<<16);
  *(uint4*)&Cf[(size_t)fi*512 + l*8] = o;
}

// ---------------------------------------------------------------------------
// A_glob TRANSPOSED: AgT[e][CTOT] fp16.
__global__ __launch_bounds__(256) void k_edge_mlp(
    const float* __restrict__ ea, const float* __restrict__ We1,
    const float* __restrict__ be1, u16* __restrict__ AgT, int E, int Epad)
{
  __shared__ float Al[128][66];
  int t = threadIdx.x;
  int e0 = blockIdx.x * 64;
  int el = t & 63, cg = t >> 6;
  int e = e0 + el;
  float4 av = make_float4(0,0,0,0);
  if (e < E) av = *(const float4*)&ea[(size_t)e*4];
  for (int cc = 0; cc < 32; ++cc){
    int c = cg*32 + cc;
    float v = be1[c] + av.x*We1[c] + av.y*We1[128+c] + av.z*We1[256+c] + av.w*We1[384+c];
    Al[c][el] = fmaxf(v, 0.f);
  }
  __syncthreads();
  for (int idx = t; idx < 64*33; idx += 256){
    int el2 = idx / 33, q = idx % 33;
    u16 ov[4];
    #pragma unroll
    for (int i=0;i<4;++i){
      int c = q*4 + i;
      float v;
      if (c < 128)       v = Al[c][el2];
      else if (c == 128) v = 1.f;
      else               v = 0.f;
      ov[i] = f2h(v);
    }
    ushort4 o; o.x=ov[0]; o.y=ov[1]; o.z=ov[2]; o.w=ov[3];
    *(ushort4*)&AgT[(size_t)(e0+el2)*CTOT + q*4] = o;
  }
}

// ---------------------------------------------------------------------------
// Fused msg + segment_sum via MFMA (v10 EXACT, r17's proven config):
// 512 thr = eg(4, 32 edges) x half(2, 66 c-slots as 33 x 16KB chunks).
__global__ __launch_bounds__(512,4) void k_msg_mfma(
    const int* __restrict__ ei, const float* __restrict__ h,
    const u16* __restrict__ AgT, const u16* __restrict__ Bg,
    float* __restrict__ agg, int E, int Epad)
{
  __shared__ __align__(16) u16 Blds[2][2][8192];  // [half][buf][16KB]
  __shared__ int dstl[128];
  int t = threadIdx.x;
  int lane = t & 63;
  int w = t >> 6;            // 0..7
  int eg = w & 3;            // 32-edge group
  int half = w >> 2;         // K half
  int e0 = blockIdx.x * 128;
  int slot0 = half * HC;

  if (t < 128) dstl[t] = (e0 + t < E) ? ei[E + e0 + t] : -1;

  f16x8 vf[2][2];
  #pragma unroll
  for (int rt=0; rt<2; ++rt){
    int e = e0 + eg*32 + rt*16 + (lane&15);
    int src = (e < E) ? ei[e] : 0;
    const float* hp = &h[(size_t)src*64 + (lane>>4)*8];
    #pragma unroll
    for (int kh=0; kh<2; ++kh){
      float4 a = *(const float4*)&hp[kh*32];
      float4 b = *(const float4*)&hp[kh*32+4];
      f16x8 v;
      v[0]=(_Float16)a.x; v[1]=(_Float16)a.y; v[2]=(_Float16)a.z; v[3]=(_Float16)a.w;
      v[4]=(_Float16)b.x; v[5]=(_Float16)b.y; v[6]=(_Float16)b.z; v[7]=(_Float16)b.w;
      vf[rt][kh] = v;
    }
  }

  f32x4 acc[2][4];
  #pragma unroll
  for (int i=0;i<2;++i)
    #pragma unroll
    for (int j=0;j<4;++j)
      acc[i][j] = (f32x4){0.f,0.f,0.f,0.f};

  const u16* Ae[2];
  #pragma unroll
  for (int rt=0; rt<2; ++rt)
    Ae[rt] = AgT + (size_t)(e0 + eg*32 + rt*16 + (lane&15))*CTOT + slot0;

  union UA { ushort2 u; _Float16 hv[2]; };
  _Float16 arP[2][2], arN[2][2];
  #pragma unroll
  for (int rt=0;rt<2;++rt){
    UA ua; ua.u = *(const ushort2*)&Ae[rt][0];
    arP[rt][0] = ua.hv[0]; arP[rt][1] = ua.hv[1];
  }

  {
    const char* g = (const char*)(Bg + (size_t)slot0*4096);
    #pragma unroll
    for (int r=0;r<4;++r)
      GLOAD_LDS16(g + r*4096 + eg*1024 + lane*16,
                  (char*)&Blds[half][0][0] + r*4096 + eg*1024);
  }
  __syncthreads();

  int cur = 0;
  for (int ci = 0; ci < 33; ++ci){
    if (ci + 1 < 33){
      const char* g = (const char*)(Bg + (size_t)(slot0 + (ci+1)*2)*4096);
      #pragma unroll
      for (int r=0;r<4;++r)
        GLOAD_LDS16(g + r*4096 + eg*1024 + lane*16,
                    (char*)&Blds[half][cur^1][0] + r*4096 + eg*1024);
      #pragma unroll
      for (int rt=0;rt<2;++rt){
        UA ua; ua.u = *(const ushort2*)&Ae[rt][(ci+1)*2];
        arN[rt][0] = ua.hv[0]; arN[rt][1] = ua.hv[1];
      }
    }
    const u16* Bb = &Blds[half][cur][0];
    #pragma unroll
    for (int cl=0; cl<2; ++cl){
      #pragma unroll
      for (int kh=0; kh<2; ++kh){
        f16x8 g0 = vmul8(vf[0][kh], arP[0][cl]);
        f16x8 g1 = vmul8(vf[1][kh], arP[1][cl]);
        #pragma unroll
        for (int ct=0; ct<4; ++ct){
          f16x8 bf = *(const f16x8*)&Bb[(cl*8 + kh*4 + ct)*512 + lane*8];
          acc[0][ct] = __builtin_amdgcn_mfma_f32_16x16x32_f16(g0, bf, acc[0][ct], 0,0,0);
          acc[1][ct] = __builtin_amdgcn_mfma_f32_16x16x32_f16(g1, bf, acc[1][ct], 0,0,0);
        }
      }
    }
    __syncthreads();
    #pragma unroll
    for (int rt=0;rt<2;++rt){ arP[rt][0] = arN[rt][0]; arP[rt][1] = arN[rt][1]; }
    cur ^= 1;
  }

  float* accl = (float*)&Blds[0][0][0];
  if (half == 1){
    #pragma unroll
    for (int rt=0; rt<2; ++rt)
      #pragma unroll
      for (int ct=0; ct<4; ++ct)
        *(f32x4*)&accl[(size_t)(eg*8 + rt*4 + ct)*256 + lane*4] = acc[rt][ct];
  }
  __syncthreads();
  if (half == 0){
    #pragma unroll
    for (int rt=0; rt<2; ++rt)
      #pragma unroll
      for (int ct=0; ct<4; ++ct)
        acc[rt][ct] += *(const f32x4*)&accl[(size_t)(eg*8 + rt*4 + ct)*256 + lane*4];
    #pragma unroll
    for (int rt=0; rt<2; ++rt){
      #pragma unroll
      for (int r=0; r<4; ++r){
        int el = eg*32 + rt*16 + (lane>>4)*4 + r;
        int dv = dstl[el];
        if (dv >= 0){
          #pragma unroll
          for (int ct=0; ct<4; ++ct)
            unsafeAtomicAdd(&agg[(size_t)dv*64 + ct*16 + (lane&15)], acc[rt][ct][r]);
        }
      }
    }
  }
}

// ---------------------------------------------------------------------------
// combine v3 (MFMA): 32 nodes/block, 4 waves.
__global__ __launch_bounds__(256) void k_combine(
    const float* __restrict__ hcur, float* __restrict__ agg,
    const u16* __restrict__ Cf, const float* __restrict__ convb,
    const float* __restrict__ bih, const float* __restrict__ bhh,
    float* __restrict__ hnext, int N)
{
  __shared__ __align__(16) u16  hn[32][72];    // h fp16 (node-major)
  __shared__ __align__(16) u16  mn[32][72];    // m fp16
  __shared__ float hsf[32][68];                // h fp32 (for GRU blend)
  int t = threadIdx.x;
  int lane = t & 63;
  int w = t >> 6;
  int lr = lane & 15, lq = lane >> 4;
  int n0 = blockIdx.x * 32;

  {
    int node = t >> 3, k8 = (t & 7) * 8;
    int n = n0 + node;
    f16x8 v;
    float4 a = make_float4(0,0,0,0), b = make_float4(0,0,0,0);
    if (n < N){
      a = *(const float4*)&hcur[(size_t)n*64 + k8];
      b = *(const float4*)&hcur[(size_t)n*64 + k8 + 4];
    }
    v[0]=(_Float16)a.x; v[1]=(_Float16)a.y; v[2]=(_Float16)a.z; v[3]=(_Float16)a.w;
    v[4]=(_Float16)b.x; v[5]=(_Float16)b.y; v[6]=(_Float16)b.z; v[7]=(_Float16)b.w;
    *(f16x8*)&hn[node][k8] = v;
    *(float4*)&hsf[node][k8] = a;
    *(float4*)&hsf[node][k8+4] = b;
  }
  __syncthreads();

  // m phase: wave w -> cols w*16..+15
  {
    f32x4 acc[2];
    acc[0] = (f32x4){0.f,0.f,0.f,0.f}; acc[1] = (f32x4){0.f,0.f,0.f,0.f};
    #pragma unroll
    for (int kh=0; kh<2; ++kh){
      f16x8 bf = *(const f16x8*)&Cf[(size_t)(w*2 + kh)*512 + lane*8];
      #pragma unroll
      for (int rt=0; rt<2; ++rt){
        f16x8 af = *(const f16x8*)&hn[rt*16 + lr][kh*32 + lq*8];
        acc[rt] = __builtin_amdgcn_mfma_f32_16x16x32_f16(af, bf, acc[rt], 0,0,0);
      }
    }
    float cb = convb[w*16 + lr];
    #pragma unroll
    for (int rt=0; rt<2; ++rt){
      #pragma unroll
      for (int r=0; r<4; ++r){
        int node = rt*16 + lq*4 + r;
        int n = n0 + node;
        int col = w*16 + lr;
        float ag = 0.f;
        if (n < N){
          ag = agg[(size_t)n*64 + col];
          agg[(size_t)n*64 + col] = 0.f;
        }
        mn[node][col] = f2h(fmaxf(acc[rt][r] + ag + cb, 0.f));
      }
    }
  }
  __syncthreads();

  f32x4 gi[3][2], gh[3][2];
  #pragma unroll
  for (int s=0;s<3;++s)
    #pragma unroll
    for (int rt=0;rt<2;++rt){
      gi[s][rt] = (f32x4){0.f,0.f,0.f,0.f};
      gh[s][rt] = (f32x4){0.f,0.f,0.f,0.f};
    }
  #pragma unroll
  for (int s=0; s<3; ++s){
    int cti = s*4 + w;
    #pragma unroll
    for (int kh=0; kh<2; ++kh){
      f16x8 bfI = *(const f16x8*)&Cf[(size_t)(8  + cti*2 + kh)*512 + lane*8];
      f16x8 bfH = *(const f16x8*)&Cf[(size_t)(32 + cti*2 + kh)*512 + lane*8];
      #pragma unroll
      for (int rt=0; rt<2; ++rt){
        f16x8 am = *(const f16x8*)&mn[rt*16 + lr][kh*32 + lq*8];
        f16x8 ah = *(const f16x8*)&hn[rt*16 + lr][kh*32 + lq*8];
        gi[s][rt] = __builtin_amdgcn_mfma_f32_16x16x32_f16(am, bfI, gi[s][rt], 0,0,0);
        gh[s][rt] = __builtin_amdgcn_mfma_f32_16x16x32_f16(ah, bfH, gh[s][rt], 0,0,0);
      }
    }
  }

  {
    int j = w*16 + lr;
    float bI0 = bih[j], bI1 = bih[64 + j], bI2 = bih[128 + j];
    float bH0 = bhh[j], bH1 = bhh[64 + j], bH2 = bhh[128 + j];
    #pragma unroll
    for (int rt=0; rt<2; ++rt){
      #pragma unroll
      for (int r=0; r<4; ++r){
        int node = rt*16 + lq*4 + r;
        int n = n0 + node;
        if (n < N){
          float rr = sigm(gi[0][rt][r] + bI0 + gh[0][rt][r] + bH0);
          float zz = sigm(gi[1][rt][r] + bI1 + gh[1][rt][r] + bH1);
          float hold = hsf[node][j];
          float nn = tanhx(gi[2][rt][r] + bI2 + rr*(gh[2][rt][r] + bH2));
          hnext[(size_t)n*64 + j] = (1.f - zz)*nn + zz*hold;
        }
      }
    }
  }
}

// ---------------------------------------------------------------------------
// final v3 (MFMA, unchanged from r14).
__global__ __launch_bounds__(256) void k_final(
    const float* __restrict__ h, const int* __restrict__ x, const float* __restrict__ ext,
    const u16* __restrict__ Wf,
    const float* __restrict__ bo1, const float* __restrict__ bo2,
    const float* __restrict__ bc1, const float* __restrict__ bc2,
    float* __restrict__ fg_out, float* __restrict__ pred_out, int N)
{
  __shared__ __align__(16) u16 fgn[32][104];  // h -> out2 -> fg (cols 0..95)
  __shared__ __align__(16) u16 t1n[32][264];  // o1 (0..63) -> t1 (0..255)
  int t = threadIdx.x;
  int lane = t & 63;
  int w = t >> 6;
  int lr = lane & 15, lq = lane >> 4;
  int n0 = blockIdx.x * 32;

  {
    int node = t >> 3, k8 = (t & 7) * 8;
    int n = n0 + node;
    f16x8 v;
    if (n < N){
      float4 a = *(const float4*)&h[(size_t)n*64 + k8];
      float4 b = *(const float4*)&h[(size_t)n*64 + k8 + 4];
      v[0]=(_Float16)a.x; v[1]=(_Float16)a.y; v[2]=(_Float16)a.z; v[3]=(_Float16)a.w;
      v[4]=(_Float16)b.x; v[5]=(_Float16)b.y; v[6]=(_Float16)b.z; v[7]=(_Float16)b.w;
    } else {
      #pragma unroll
      for (int i=0;i<8;++i) v[i] = (_Float16)0.f;
    }
    *(f16x8*)&fgn[node][k8] = v;
    if (t < 160){
      int node2 = t / 5, qd = t % 5;
      *(uint4*)&fgn[node2][64 + qd*8] = make_uint4(0,0,0,0);
    }
  }
  __syncthreads();

  // P1: o1 = relu(h@Wo1 + bo1)
  {
    f32x4 acc[2];
    acc[0] = (f32x4){0.f,0.f,0.f,0.f}; acc[1] = (f32x4){0.f,0.f,0.f,0.f};
    #pragma unroll
    for (int kh=0; kh<2; ++kh){
      f16x8 bf = *(const f16x8*)&Wf[(size_t)(w*2 + kh)*512 + lane*8];
      #pragma unroll
      for (int rt=0; rt<2; ++rt){
        f16x8 af = *(const f16x8*)&fgn[rt*16 + lr][kh*32 + lq*8];
        acc[rt] = __builtin_amdgcn_mfma_f32_16x16x32_f16(af, bf, acc[rt], 0,0,0);
      }
    }
    float bv = bo1[w*16 + lr];
    #pragma unroll
    for (int rt=0; rt<2; ++rt)
      #pragma unroll
      for (int r=0; r<4; ++r)
        t1n[rt*16 + lq*4 + r][w*16 + lr] = f2h(fmaxf(acc[rt][r] + bv, 0.f));
  }
  __syncthreads();

  // P2: out2 = o1@Wo2 + bo2 -> fgn
  {
    f32x4 acc[2];
    acc[0] = (f32x4){0.f,0.f,0.f,0.f}; acc[1] = (f32x4){0.f,0.f,0.f,0.f};
    #pragma unroll
    for (int kh=0; kh<2; ++kh){
      f16x8 bf = *(const f16x8*)&Wf[(size_t)(8 + w*2 + kh)*512 + lane*8];
      #pragma unroll
      for (int rt=0; rt<2; ++rt){
        f16x8 af = *(const f16x8*)&t1n[rt*16 + lr][kh*32 + lq*8];
        acc[rt] = __builtin_amdgcn_mfma_f32_16x16x32_f16(af, bf, acc[rt], 0,0,0);
      }
    }
    float bv = bo2[w*16 + lr];
    #pragma unroll
    for (int rt=0; rt<2; ++rt)
      #pragma unroll
      for (int r=0; r<4; ++r)
        fgn[rt*16 + lq*4 + r][w*16 + lr] = f2h(acc[rt][r] + bv);
  }
  __syncthreads();

  if (t < 32){
    int ni = t, n = n0 + ni;
    if (n < N){
      int idxn = x[n];
      float e0=ext[n*3], e1=ext[n*3+1], e2=ext[n*3+2];
      float ss = 1.f + e0*e0 + e1*e1 + e2*e2;
      for (int j=0;j<64;++j){ float v = hbits2f(fgn[ni][j]); ss += v*v; }
      float rn = 1.f / fmaxf(sqrtf(ss), 1e-12f);
      for (int j=0;j<64;++j) fgn[ni][j] = f2h(hbits2f(fgn[ni][j])*rn);
      #pragma unroll
      for (int c=0;c<24;++c) fgn[ni][64+c] = (c==idxn) ? f2h(rn) : (u16)0;
      fgn[ni][88] = f2h(e0*rn); fgn[ni][89] = f2h(e1*rn); fgn[ni][90] = f2h(e2*rn);
    }
  }
  __syncthreads();

  for (int idx=t; idx<32*91; idx+=256){
    int ni = idx / 91, c = idx % 91;
    int n = n0 + ni;
    if (n < N) fg_out[(size_t)n*91 + c] = hbits2f(fgn[ni][c]);
  }

  // P5: t1 = relu(fg@Wc1 + bc1), K=96
  {
    f32x4 acc[2][4];
    #pragma unroll
    for (int i=0;i<2;++i)
      #pragma unroll
      for (int j=0;j<4;++j) acc[i][j] = (f32x4){0.f,0.f,0.f,0.f};
    #pragma unroll
    for (int kh=0; kh<3; ++kh){
      f16x8 af[2];
      #pragma unroll
      for (int rt=0; rt<2; ++rt)
        af[rt] = *(const f16x8*)&fgn[rt*16 + lr][kh*32 + lq*8];
      #pragma unroll
      for (int c4=0; c4<4; ++c4){
        int cti = w*4 + c4;
        f16x8 bf = *(const f16x8*)&Wf[(size_t)(16 + cti*3 + kh)*512 + lane*8];
        #pragma unroll
        for (int rt=0; rt<2; ++rt)
          acc[rt][c4] = __builtin_amdgcn_mfma_f32_16x16x32_f16(af[rt], bf, acc[rt][c4], 0,0,0);
      }
    }
    #pragma unroll
    for (int c4=0; c4<4; ++c4){
      float bv = bc1[w*64 + c4*16 + lr];
      #pragma unroll
      for (int rt=0; rt<2; ++rt)
        #pragma unroll
        for (int r=0; r<4; ++r)
          t1n[rt*16 + lq*4 + r][w*64 + c4*16 + lr] = f2h(fmaxf(acc[rt][c4][r] + bv, 0.f));
    }
  }
  __syncthreads();

  // P6: pred = t1@Wc2 + bc2
  {
    int rt = w >> 1, ct = w & 1;
    f32x4 acc = (f32x4){0.f,0.f,0.f,0.f};
    #pragma unroll
    for (int kh=0; kh<8; ++kh){
      f16x8 af = *(const f16x8*)&t1n[rt*16 + lr][kh*32 + lq*8];
      f16x8 bf = *(const f16x8*)&Wf[(size_t)(64 + kh*2 + ct)*512 + lane*8];
      acc = __builtin_amdgcn_mfma_f32_16x16x32_f16(af, bf, acc, 0,0,0);
    }
    int c = ct*16 + lr;
    if (c < 18){
      float bv = bc2[c];
      #pragma unroll
      for (int r=0; r<4; ++r){
        int n = n0 + rt*16 + lq*4 + r;
        if (n < N) pred_out[(size_t)n*18 + c] = acc[r] + bv;
      }
    }
  }
}

// ---------------------------------------------------------------------------
extern "C" void kernel_launch(void* const* d_in, const int* in_sizes, int n_in,
                              void* d_out, int out_size, void* d_ws, size_t ws_size,
                              hipStream_t stream)
{
  const int*   x    = (const int*)d_in[0];
  const int*   ei   = (const int*)d_in[1];
  const float* ea   = (const float*)d_in[2];
  const float* ext  = (const float*)d_in[3];
  const float* embed= (const float*)d_in[4];
  const float* We1  = (const float*)d_in[5];
  const float* be1  = (const float*)d_in[6];
  const float* We2  = (const float*)d_in[7];
  const float* be2  = (const float*)d_in[8];
  const float* root = (const float*)d_in[9];
  const float* convb= (const float*)d_in[10];
  const float* Wih  = (const float*)d_in[11];
  const float* Whh  = (const float*)d_in[12];
  const float* bih  = (const float*)d_in[13];
  const float* bhh  = (const float*)d_in[14];
  const float* Wo1  = (const float*)d_in[15];
  const float* bo1  = (const float*)d_in[16];
  const float* Wo2  = (const float*)d_in[17];
  const float* bo2  = (const float*)d_in[18];
  const float* Wc1  = (const float*)d_in[19];
  const float* bc1  = (const float*)d_in[20];
  const float* Wc2  = (const float*)d_in[21];
  const float* bc2  = (const float*)d_in[22];
  int N = in_sizes[0];
  int E = in_sizes[1] / 2;
  float* out = (float*)d_out;
  float* fg_out = out;
  float* pred_out = out + (size_t)N*91;

  int nblk256 = (E + 255) / 256;
  int Epad = nblk256 * 256;
  int nblk128 = (E + 127) / 128;

  char* w = (char*)d_ws;
  size_t remain = ws_size;
  auto alloc = [&](size_t bytes)->char*{
    size_t rb = (bytes + 255) & ~(size_t)255;
    if (rb > remain) return (char*)0;
    char* p = w; w += rb; remain -= rb; return p;
  };
  float* h_a  = (float*)alloc((size_t)N*64*4);
  float* h_b  = (float*)alloc((size_t)N*64*4);
  float* agg  = (float*)alloc((size_t)N*64*4);
  u16*   AgT  = (u16*)alloc((size_t)Epad*CTOT*2);
  u16*   Bg   = (u16*)alloc((size_t)CTOT*8192);
  u16*   Wf   = (u16*)alloc((size_t)80*512*2);
  u16*   Cf   = (u16*)alloc((size_t)56*512*2);
  if (!h_a || !h_b || !agg || !AgT || !Bg || !Wf || !Cf) return;

  k_init_h<<<dim3((N*64 + 255)/256), dim3(256), 0, stream>>>(x, embed, ext, h_a, N);
  k_prep_B<<<dim3((CTOT*8*64 + 255)/256), dim3(256), 0, stream>>>(We2, be2, Bg);
  k_prep_W<<<dim3((80*64 + 255)/256), dim3(256), 0, stream>>>(Wo1, Wo2, Wc1, Wc2, Wf);
  k_prep_C<<<dim3((56*64 + 255)/256), dim3(256), 0, stream>>>(root, Wih, Whh, Cf);
  k_edge_mlp<<<dim3(Epad/64), dim3(256), 0, stream>>>(ea, We1, be1, AgT, E, Epad);
  hipMemsetAsync(agg, 0, (size_t)N*64*4, stream);

  float* hc = h_a; float* hn = h_b;
  for (int it = 0; it < NITERS; ++it){
    k_msg_mfma<<<dim3(nblk128), dim3(512), 0, stream>>>(ei, hc, AgT, Bg, agg, E, Epad);
    k_combine<<<dim3((N + 31)/32), dim3(256), 0, stream>>>(
        hc, agg, Cf, convb, bih, bhh, hn, N);
    float* tmp = hc; hc = hn; hn = tmp;
  }

  k_final<<<dim3((N + 31)/32), dim3(256), 0, stream>>>(
      hc, x, ext, Wf, bo1, bo2, bc1, bc2, fg_out, pred_out, N);
}